// Round 1
// baseline (461.964 us; speedup 1.0000x reference)
//
#include <hip/hip_runtime.h>
#include <hip/hip_bf16.h>

typedef __bf16 bf16x8 __attribute__((ext_vector_type(8)));
typedef __bf16 bf16x4 __attribute__((ext_vector_type(4)));
typedef float f32x4 __attribute__((ext_vector_type(4)));

#define MFMA(a, b, c) __builtin_amdgcn_mfma_f32_16x16x32_bf16((a), (b), (c), 0, 0, 0)

// ---------------- GroupNorm: stats (one block per (b,g)) ----------------
__global__ __launch_bounds__(256) void gn_stats(const float* __restrict__ x,
                                                float* __restrict__ stats) {
    int bg = blockIdx.x;          // 0..31
    int b = bg >> 3, g = bg & 7;
    const float* base = x + (size_t)b * 4096 * 256 + g * 32;
    float s = 0.f, s2 = 0.f;
    // 4096 positions * 8 float4 per position
    for (int i = threadIdx.x; i < 4096 * 8; i += 256) {
        int pos = i >> 3, f4 = i & 7;
        float4 v = *(const float4*)(base + (size_t)pos * 256 + f4 * 4);
        s  += v.x + v.y + v.z + v.w;
        s2 += v.x * v.x + v.y * v.y + v.z * v.z + v.w * v.w;
    }
    for (int off = 32; off; off >>= 1) {
        s  += __shfl_down(s, off);
        s2 += __shfl_down(s2, off);
    }
    __shared__ float red[8];
    int wave = threadIdx.x >> 6, lane = threadIdx.x & 63;
    if (lane == 0) { red[wave] = s; red[4 + wave] = s2; }
    __syncthreads();
    if (threadIdx.x == 0) {
        float S = red[0] + red[1] + red[2] + red[3];
        float S2 = red[4] + red[5] + red[6] + red[7];
        const float invN = 1.f / 131072.f;
        float mean = S * invN;
        float var = S2 * invN - mean * mean;
        stats[bg * 2] = mean;
        stats[bg * 2 + 1] = rsqrtf(var + 1e-3f);
    }
}

// ---------------- GroupNorm: normalize; fp32 -> d_out, bf16 -> ws ----------------
__global__ __launch_bounds__(256) void gn_norm(const float* __restrict__ x,
                                               const float* __restrict__ gamma,
                                               const float* __restrict__ beta,
                                               const float* __restrict__ stats,
                                               float* __restrict__ xn_f32,
                                               __bf16* __restrict__ xn_bf) {
    size_t idx = (size_t)blockIdx.x * 256 + threadIdx.x;  // over 1,048,576 float4
    int c4 = (int)(idx & 63);
    int row = (int)(idx >> 6);
    int b = row >> 12;
    int g = c4 >> 3;
    float mean = stats[(b * 8 + g) * 2];
    float rstd = stats[(b * 8 + g) * 2 + 1];
    float4 xv = ((const float4*)x)[idx];
    float4 ga = ((const float4*)gamma)[c4];
    float4 be = ((const float4*)beta)[c4];
    float4 r;
    r.x = (xv.x - mean) * rstd * ga.x + be.x;
    r.y = (xv.y - mean) * rstd * ga.y + be.y;
    r.z = (xv.z - mean) * rstd * ga.z + be.z;
    r.w = (xv.w - mean) * rstd * ga.w + be.w;
    ((float4*)xn_f32)[idx] = r;
    bf16x4 o;
    o[0] = (__bf16)r.x; o[1] = (__bf16)r.y; o[2] = (__bf16)r.z; o[3] = (__bf16)r.w;
    *(bf16x4*)(xn_bf + idx * 4) = o;
}

// ---------------- Weight prep: fp32 [k][n] -> bf16 [n][k], 4 weights ----------------
__global__ __launch_bounds__(256) void prep_w(const float* __restrict__ Wq,
                                              const float* __restrict__ Wk,
                                              const float* __restrict__ Wv,
                                              const float* __restrict__ Wp,
                                              __bf16* __restrict__ wt) {
    int tid = blockIdx.x * 256 + threadIdx.x;  // 0..262143
    int w = tid >> 16;
    int id = tid & 65535;
    int n = id & 255;   // coalesced read along n
    int k = id >> 8;
    const float* W = (w == 0) ? Wq : (w == 1) ? Wk : (w == 2) ? Wv : Wp;
    wt[(size_t)w * 65536 + n * 256 + k] = (__bf16)W[k * 256 + n];
}

// ---------------- QKV GEMM: [16384,256] @ [256,256], MFMA, no LDS (K=256) ----------------
__global__ __launch_bounds__(256) void qkv_gemm(const __bf16* __restrict__ xn,
                                                const __bf16* __restrict__ wt,
                                                const float* __restrict__ bq,
                                                const float* __restrict__ bk,
                                                const float* __restrict__ bv,
                                                __bf16* __restrict__ qout,
                                                __bf16* __restrict__ kout,
                                                __bf16* __restrict__ vtout) {
    int w = blockIdx.z;
    const __bf16* W = wt + (size_t)w * 65536;
    int wave = threadIdx.x >> 6, lane = threadIdx.x & 63;
    int quad = lane >> 4, l16 = lane & 15;
    int m0 = blockIdx.x * 64 + wave * 16;
    int n0 = blockIdx.y * 64;
    f32x4 acc[4] = {{0.f,0.f,0.f,0.f},{0.f,0.f,0.f,0.f},{0.f,0.f,0.f,0.f},{0.f,0.f,0.f,0.f}};
    const __bf16* arow = xn + (size_t)(m0 + l16) * 256 + quad * 8;
#pragma unroll
    for (int k = 0; k < 256; k += 32) {
        bf16x8 af = *(const bf16x8*)(arow + k);
#pragma unroll
        for (int ct = 0; ct < 4; ct++) {
            bf16x8 bf = *(const bf16x8*)(W + (size_t)(n0 + ct * 16 + l16) * 256 + k + quad * 8);
            acc[ct] = MFMA(af, bf, acc[ct]);
        }
    }
    const float* bias = (w == 0) ? bq : (w == 1) ? bk : bv;
#pragma unroll
    for (int ct = 0; ct < 4; ct++) {
        int c = n0 + ct * 16 + l16;
        float bias_v = bias[c];
#pragma unroll
        for (int r = 0; r < 4; r++) {
            int m = m0 + quad * 4 + r;
            float val = acc[ct][r] + bias_v;
            if (w == 2) {
                int b = m >> 12, n = m & 4095;
                vtout[((size_t)(b * 256 + c)) * 4096 + n] = (__bf16)val;
            } else if (w == 0) {
                qout[(size_t)m * 256 + c] = (__bf16)val;
            } else {
                kout[(size_t)m * 256 + c] = (__bf16)val;
            }
        }
    }
}

// ---------------- Flash attention: BM=64 (4 waves x 16 rows), 32-key tiles ----------------
__global__ __launch_bounds__(256) void flash_attn(const __bf16* __restrict__ q,
                                                  const __bf16* __restrict__ k,
                                                  const __bf16* __restrict__ vt,
                                                  __bf16* __restrict__ ao) {
    __shared__ __bf16 ktile[32][264];    // keys x C, +8 pad -> 2-way conflicts only
    __shared__ __bf16 vtile[256][40];    // C x keys, +8 pad
    __shared__ __bf16 ptile[4][16][40];  // per-wave P round-trip, +8 pad
    int wave = threadIdx.x >> 6, lane = threadIdx.x & 63;
    int quad = lane >> 4, l16 = lane & 15;
    int b = blockIdx.y;
    int q0 = blockIdx.x * 64;

    // Q fragments for this wave's 16 rows, all of C=256 (8 k-frags), scaled later in S
    bf16x8 qf[8];
    const __bf16* qbase = q + ((size_t)b * 4096 + q0 + wave * 16 + l16) * 256 + quad * 8;
#pragma unroll
    for (int f = 0; f < 8; f++) qf[f] = *(const bf16x8*)(qbase + f * 32);

    f32x4 oacc[16];
#pragma unroll
    for (int ct = 0; ct < 16; ct++) oacc[ct] = (f32x4){0.f, 0.f, 0.f, 0.f};
    float mi[4], li[4];
#pragma unroll
    for (int r = 0; r < 4; r++) { mi[r] = -1e30f; li[r] = 0.f; }

    const __bf16* kb = k + (size_t)b * 4096 * 256;
    const __bf16* vb = vt + (size_t)b * 256 * 4096;

    for (int kt = 0; kt < 4096; kt += 32) {
        __syncthreads();
        // stage K tile: 32 rows x 256 ch = 1024 chunks of 8 bf16
#pragma unroll
        for (int i = 0; i < 4; i++) {
            int chunk = threadIdx.x + i * 256;
            int row = chunk >> 5, c8 = chunk & 31;
            *(bf16x8*)&ktile[row][c8 * 8] = *(const bf16x8*)(kb + (size_t)(kt + row) * 256 + c8 * 8);
        }
        // stage V tile (transposed source): 256 c-rows x 32 keys
#pragma unroll
        for (int i = 0; i < 4; i++) {
            int chunk = threadIdx.x + i * 256;
            int c = chunk >> 2, m8 = chunk & 3;
            *(bf16x8*)&vtile[c][m8 * 8] = *(const bf16x8*)(vb + (size_t)c * 4096 + kt + m8 * 8);
        }
        __syncthreads();

        // S = Q K^T for 16 rows x 32 keys (two 16x16 subtiles)
        f32x4 s0 = {0.f,0.f,0.f,0.f}, s1 = {0.f,0.f,0.f,0.f};
#pragma unroll
        for (int f = 0; f < 8; f++) {
            bf16x8 b0 = *(const bf16x8*)&ktile[l16][f * 32 + quad * 8];
            bf16x8 b1 = *(const bf16x8*)&ktile[16 + l16][f * 32 + quad * 8];
            s0 = MFMA(qf[f], b0, s0);
            s1 = MFMA(qf[f], b1, s1);
        }

        // online softmax per row (row = quad*4 + r; cols spread over the 16 lanes of quad)
        float alpha[4];
#pragma unroll
        for (int r = 0; r < 4; r++) {
            float sa = s0[r] * 0.0625f;
            float sb = s1[r] * 0.0625f;
            float mx = fmaxf(sa, sb);
#pragma unroll
            for (int off = 8; off; off >>= 1) mx = fmaxf(mx, __shfl_xor(mx, off));
            float mn = fmaxf(mi[r], mx);
            alpha[r] = __expf(mi[r] - mn);
            float p0 = __expf(sa - mn);
            float p1 = __expf(sb - mn);
            float rs = p0 + p1;
#pragma unroll
            for (int off = 8; off; off >>= 1) rs += __shfl_xor(rs, off);
            li[r] = alpha[r] * li[r] + rs;
            mi[r] = mn;
            ptile[wave][quad * 4 + r][l16] = (__bf16)p0;
            ptile[wave][quad * 4 + r][16 + l16] = (__bf16)p1;
        }
        // rescale O
#pragma unroll
        for (int ct = 0; ct < 16; ct++) {
#pragma unroll
            for (int r = 0; r < 4; r++) oacc[ct][r] *= alpha[r];
        }
        // P (A-layout via LDS round-trip) @ V
        bf16x8 af = *(const bf16x8*)&ptile[wave][l16][quad * 8];
#pragma unroll
        for (int ct = 0; ct < 16; ct++) {
            bf16x8 bfv = *(const bf16x8*)&vtile[ct * 16 + l16][quad * 8];
            oacc[ct] = MFMA(af, bfv, oacc[ct]);
        }
    }

    float inv[4];
#pragma unroll
    for (int r = 0; r < 4; r++) inv[r] = 1.f / li[r];
    __bf16* orow = ao + ((size_t)b * 4096 + q0 + wave * 16) * 256;
#pragma unroll
    for (int ct = 0; ct < 16; ct++) {
#pragma unroll
        for (int r = 0; r < 4; r++)
            orow[(quad * 4 + r) * 256 + ct * 16 + l16] = (__bf16)(oacc[ct][r] * inv[r]);
    }
}

// ---------------- Projection GEMM + bias + residual (d_out already holds xn) ----------------
__global__ __launch_bounds__(256) void proj_gemm(const __bf16* __restrict__ ao,
                                                 const __bf16* __restrict__ wpt,
                                                 const float* __restrict__ bp,
                                                 float* __restrict__ out) {
    int wave = threadIdx.x >> 6, lane = threadIdx.x & 63;
    int quad = lane >> 4, l16 = lane & 15;
    int m0 = blockIdx.x * 64 + wave * 16;
    int n0 = blockIdx.y * 64;
    f32x4 acc[4] = {{0.f,0.f,0.f,0.f},{0.f,0.f,0.f,0.f},{0.f,0.f,0.f,0.f},{0.f,0.f,0.f,0.f}};
    const __bf16* arow = ao + (size_t)(m0 + l16) * 256 + quad * 8;
#pragma unroll
    for (int k = 0; k < 256; k += 32) {
        bf16x8 af = *(const bf16x8*)(arow + k);
#pragma unroll
        for (int ct = 0; ct < 4; ct++) {
            bf16x8 bf = *(const bf16x8*)(wpt + (size_t)(n0 + ct * 16 + l16) * 256 + k + quad * 8);
            acc[ct] = MFMA(af, bf, acc[ct]);
        }
    }
#pragma unroll
    for (int ct = 0; ct < 4; ct++) {
        int c = n0 + ct * 16 + l16;
        float bias_v = bp[c];
#pragma unroll
        for (int r = 0; r < 4; r++) {
            int m = m0 + quad * 4 + r;
            size_t idx = (size_t)m * 256 + c;
            out[idx] = out[idx] + acc[ct][r] + bias_v;
        }
    }
}

extern "C" void kernel_launch(void* const* d_in, const int* in_sizes, int n_in,
                              void* d_out, int out_size, void* d_ws, size_t ws_size,
                              hipStream_t stream) {
    const float* x     = (const float*)d_in[0];
    const float* gamma = (const float*)d_in[1];
    const float* beta  = (const float*)d_in[2];
    const float* Wq    = (const float*)d_in[3];
    const float* bq    = (const float*)d_in[4];
    const float* Wk    = (const float*)d_in[5];
    const float* bk    = (const float*)d_in[6];
    const float* Wv    = (const float*)d_in[7];
    const float* bv    = (const float*)d_in[8];
    const float* Wp    = (const float*)d_in[9];
    const float* bp    = (const float*)d_in[10];
    float* out = (float*)d_out;

    char* ws = (char*)d_ws;
    __bf16* xn_bf   = (__bf16*)(ws);                    // 8,388,608 B
    __bf16* wt      = (__bf16*)(ws + 8388608);          //   524,288 B (4 x 256x256 bf16)
    __bf16* qbuf    = (__bf16*)(ws + 8912896);          // 8,388,608 B
    __bf16* kbuf    = (__bf16*)(ws + 17301504);         // 8,388,608 B
    __bf16* vtbuf   = (__bf16*)(ws + 25690112);         // 8,388,608 B
    __bf16* aobuf   = (__bf16*)(ws + 34078720);         // 8,388,608 B
    float*  stats   = (float*)(ws + 42467328);          //       256 B

    gn_stats<<<32, 256, 0, stream>>>(x, stats);
    gn_norm<<<4096, 256, 0, stream>>>(x, gamma, beta, stats, out, xn_bf);
    prep_w<<<1024, 256, 0, stream>>>(Wq, Wk, Wv, Wp, wt);
    qkv_gemm<<<dim3(256, 4, 3), 256, 0, stream>>>(xn_bf, wt, bq, bk, bv, qbuf, kbuf, vtbuf);
    flash_attn<<<dim3(64, 4), 256, 0, stream>>>(qbuf, kbuf, vtbuf, aobuf);
    proj_gemm<<<dim3(256, 4), 256, 0, stream>>>(aobuf, wt + 3 * 65536, bp, out);
}

// Round 2
// 366.201 us; speedup vs baseline: 1.2615x; 1.2615x over previous
//
#include <hip/hip_runtime.h>
#include <hip/hip_bf16.h>

typedef __bf16 bf16x8 __attribute__((ext_vector_type(8)));
typedef __bf16 bf16x4 __attribute__((ext_vector_type(4)));
typedef float f32x4 __attribute__((ext_vector_type(4)));
typedef float f32x16 __attribute__((ext_vector_type(16)));

#define MFMA16(a,b,c) __builtin_amdgcn_mfma_f32_16x16x32_bf16((a),(b),(c),0,0,0)
#define MFMA32(a,b,c) __builtin_amdgcn_mfma_f32_32x32x16_bf16((a),(b),(c),0,0,0)

// ---------------- GroupNorm stats, stage 1: 512 blocks (bg x 16 slices) ----------------
__global__ __launch_bounds__(256) void gn_stats1(const float* __restrict__ x,
                                                 float* __restrict__ pstats) {
    int blk = blockIdx.x;            // 0..511
    int bg = blk >> 4, sl = blk & 15;
    int b = bg >> 3, g = bg & 7;
    const float* base = x + ((size_t)b * 4096 + sl * 256) * 256 + g * 32;
    float s = 0.f, s2 = 0.f;
    for (int i = threadIdx.x; i < 2048; i += 256) {   // 256 rows x 8 float4
        int pos = i >> 3, f4 = i & 7;
        float4 v = *(const float4*)(base + (size_t)pos * 256 + f4 * 4);
        s  += v.x + v.y + v.z + v.w;
        s2 += v.x * v.x + v.y * v.y + v.z * v.z + v.w * v.w;
    }
    for (int off = 32; off; off >>= 1) {
        s  += __shfl_down(s, off);
        s2 += __shfl_down(s2, off);
    }
    __shared__ float red[8];
    int wave = threadIdx.x >> 6, lane = threadIdx.x & 63;
    if (lane == 0) { red[wave] = s; red[4 + wave] = s2; }
    __syncthreads();
    if (threadIdx.x == 0) {
        pstats[blk * 2]     = red[0] + red[1] + red[2] + red[3];
        pstats[blk * 2 + 1] = red[4] + red[5] + red[6] + red[7];
    }
}

// ---------------- GroupNorm stats, stage 2: finalize mean/rstd ----------------
__global__ void gn_stats2(const float* __restrict__ pstats, float* __restrict__ stats) {
    int bg = threadIdx.x;
    if (bg < 32) {
        float S = 0.f, S2 = 0.f;
        for (int sl = 0; sl < 16; sl++) {
            S  += pstats[(bg * 16 + sl) * 2];
            S2 += pstats[(bg * 16 + sl) * 2 + 1];
        }
        const float invN = 1.f / 131072.f;
        float mean = S * invN;
        float var = S2 * invN - mean * mean;
        stats[bg * 2] = mean;
        stats[bg * 2 + 1] = rsqrtf(var + 1e-3f);
    }
}

// ---------------- GroupNorm normalize; fp32 -> d_out, bf16 -> ws ----------------
__global__ __launch_bounds__(256) void gn_norm(const float* __restrict__ x,
                                               const float* __restrict__ gamma,
                                               const float* __restrict__ beta,
                                               const float* __restrict__ stats,
                                               float* __restrict__ xn_f32,
                                               __bf16* __restrict__ xn_bf) {
    size_t idx = (size_t)blockIdx.x * 256 + threadIdx.x;  // over 1,048,576 float4
    int c4 = (int)(idx & 63);
    int row = (int)(idx >> 6);
    int b = row >> 12;
    int g = c4 >> 3;
    float mean = stats[(b * 8 + g) * 2];
    float rstd = stats[(b * 8 + g) * 2 + 1];
    float4 xv = ((const float4*)x)[idx];
    float4 ga = ((const float4*)gamma)[c4];
    float4 be = ((const float4*)beta)[c4];
    float4 r;
    r.x = (xv.x - mean) * rstd * ga.x + be.x;
    r.y = (xv.y - mean) * rstd * ga.y + be.y;
    r.z = (xv.z - mean) * rstd * ga.z + be.z;
    r.w = (xv.w - mean) * rstd * ga.w + be.w;
    ((float4*)xn_f32)[idx] = r;
    bf16x4 o;
    o[0] = (__bf16)r.x; o[1] = (__bf16)r.y; o[2] = (__bf16)r.z; o[3] = (__bf16)r.w;
    *(bf16x4*)(xn_bf + idx * 4) = o;
}

// ---------------- Weight prep: fp32 [k][n] -> bf16 [n][k], 4 weights ----------------
__global__ __launch_bounds__(256) void prep_w(const float* __restrict__ Wq,
                                              const float* __restrict__ Wk,
                                              const float* __restrict__ Wv,
                                              const float* __restrict__ Wp,
                                              __bf16* __restrict__ wt) {
    int tid = blockIdx.x * 256 + threadIdx.x;  // 0..262143
    int w = tid >> 16;
    int id = tid & 65535;
    int n = id & 255;   // coalesced read along n
    int k = id >> 8;
    const float* W = (w == 0) ? Wq : (w == 1) ? Wk : (w == 2) ? Wv : Wp;
    wt[(size_t)w * 65536 + n * 256 + k] = (__bf16)W[k * 256 + n];
}

// ---------------- QKV GEMM: 64 rows x 64 cols per wave, B-frags reused 4x ----------------
__global__ __launch_bounds__(256, 2) void qkv_gemm(const __bf16* __restrict__ xn,
                                                   const __bf16* __restrict__ wt,
                                                   const float* __restrict__ bq,
                                                   const float* __restrict__ bk,
                                                   const float* __restrict__ bv,
                                                   __bf16* __restrict__ qout,
                                                   __bf16* __restrict__ kout,
                                                   __bf16* __restrict__ vtout) {
    int w = blockIdx.z;
    const __bf16* W = wt + (size_t)w * 65536;
    int wave = threadIdx.x >> 6, lane = threadIdx.x & 63;
    int quad = lane >> 4, l16 = lane & 15;
    int m0 = blockIdx.x * 256 + wave * 64;
    int n0 = blockIdx.y * 64;
    bf16x8 bfr[4][8];
#pragma unroll
    for (int ct = 0; ct < 4; ct++)
#pragma unroll
        for (int kf = 0; kf < 8; kf++)
            bfr[ct][kf] = *(const bf16x8*)(W + (size_t)(n0 + ct * 16 + l16) * 256 + kf * 32 + quad * 8);
    f32x4 acc[4][4];
#pragma unroll
    for (int mt = 0; mt < 4; mt++)
#pragma unroll
        for (int ct = 0; ct < 4; ct++)
#pragma unroll
            for (int r = 0; r < 4; r++) acc[mt][ct][r] = 0.f;
#pragma unroll
    for (int kf = 0; kf < 8; kf++) {
        bf16x8 af[4];
#pragma unroll
        for (int mt = 0; mt < 4; mt++)
            af[mt] = *(const bf16x8*)(xn + (size_t)(m0 + mt * 16 + l16) * 256 + kf * 32 + quad * 8);
#pragma unroll
        for (int mt = 0; mt < 4; mt++)
#pragma unroll
            for (int ct = 0; ct < 4; ct++)
                acc[mt][ct] = MFMA16(af[mt], bfr[ct][kf], acc[mt][ct]);
    }
    const float* bias = (w == 0) ? bq : (w == 1) ? bk : bv;
#pragma unroll
    for (int mt = 0; mt < 4; mt++) {
#pragma unroll
        for (int ct = 0; ct < 4; ct++) {
            int c = n0 + ct * 16 + l16;
            float bias_v = bias[c];
#pragma unroll
            for (int r = 0; r < 4; r++) {
                int m = m0 + mt * 16 + quad * 4 + r;
                float val = acc[mt][ct][r] + bias_v;
                if (w == 2) {
                    int bb = m >> 12, n = m & 4095;
                    vtout[((size_t)(bb * 256 + c)) * 4096 + n] = (__bf16)val;
                } else if (w == 0) {
                    // pre-scale q by 1/sqrt(C)=0.0625 (exact exponent shift in bf16)
                    qout[(size_t)m * 256 + c] = (__bf16)(val * 0.0625f);
                } else {
                    kout[(size_t)m * 256 + c] = (__bf16)val;
                }
            }
        }
    }
}

// ---------------- Flash attention v2: 32x32x16 MFMA, S^T/O^T layout, ksplit=4 ----------------
// grid (32 qtiles, 4 ksplit, 4 batch) = 512 blocks, 256 thr (4 waves x 32 q-rows)
__global__ __launch_bounds__(256, 2) void flash_attn(const __bf16* __restrict__ q,
                                                     const __bf16* __restrict__ k,
                                                     const __bf16* __restrict__ vt,
                                                     __bf16* __restrict__ po,
                                                     float* __restrict__ ml) {
    __shared__ __align__(16) char smem[79872];
    __bf16 (*kbufs)[32][264] = (__bf16(*)[32][264])(smem);          // 2 x 16896 B
    __bf16 (*vbufs)[256][36] = (__bf16(*)[256][36])(smem + 33792);  // 2 x 18432 B
    __bf16 (*ptile)[32][36]  = (__bf16(*)[32][36]) (smem + 70656);  // 4 x 2304 B
    __bf16 (*otr)[32][264]   = (__bf16(*)[32][264])(smem);          // aliases k/v bufs (epilogue)

    const int tid = threadIdx.x;
    const int wave = tid >> 6, lane = tid & 63;
    const int l32 = lane & 31, h = lane >> 5;
    const int qt = blockIdx.x, ks = blockIdx.y, b = blockIdx.z;

    const int row0 = qt * 128 + wave * 32;
    const size_t rowg0 = (size_t)b * 4096 + row0;

    // Q fragments (B-operand, pre-scaled): qf[s] = Q[row0+l32][s*16 + h*8 .. +8]
    bf16x8 qf[16];
    const __bf16* qbase = q + (rowg0 + l32) * 256 + h * 8;
#pragma unroll
    for (int s = 0; s < 16; s++) qf[s] = *(const bf16x8*)(qbase + s * 16);

    f32x16 acc[8];
#pragma unroll
    for (int ct = 0; ct < 8; ct++)
#pragma unroll
        for (int r = 0; r < 16; r++) acc[ct][r] = 0.f;
    float mi = -1e30f, li = 0.f;

    const __bf16* kb = k + ((size_t)b * 4096 + ks * 1024) * 256;
    const __bf16* vb = vt + (size_t)b * 256 * 4096 + ks * 1024;

    // prologue: stage tile 0
    bf16x8 kc[4], vc[4];
#pragma unroll
    for (int i = 0; i < 4; i++) {
        int c = tid + 256 * i;
        kc[i] = *(const bf16x8*)(kb + (size_t)(c >> 5) * 256 + (c & 31) * 8);
    }
#pragma unroll
    for (int j = 0; j < 4; j++)
        vc[j] = *(const bf16x8*)(vb + (size_t)tid * 4096 + j * 8);
#pragma unroll
    for (int i = 0; i < 4; i++) {
        int c = tid + 256 * i;
        *(bf16x8*)&kbufs[0][c >> 5][(c & 31) * 8] = kc[i];
    }
#pragma unroll
    for (int j = 0; j < 4; j++)
        *(bf16x8*)&vbufs[0][tid][j * 8] = vc[j];
    __syncthreads();

    for (int it = 0; it < 32; ++it) {
        const int cur = it & 1;
        // ---- S^T = K . Q^T  (32 keys x 32 q-rows; lane owns q-row l32) ----
        f32x16 s;
#pragma unroll
        for (int r = 0; r < 16; r++) s[r] = 0.f;
#pragma unroll
        for (int kf = 0; kf < 16; kf++) {
            bf16x8 af = *(const bf16x8*)&kbufs[cur][l32][kf * 16 + h * 8];
            s = MFMA32(af, qf[kf], s);
        }
        // ---- online softmax: 16 keys in this lane, 16 in lane^32 ----
        float mx = s[0];
#pragma unroll
        for (int r = 1; r < 16; r++) mx = fmaxf(mx, s[r]);
        mx = fmaxf(mx, __shfl_xor(mx, 32));
        float mnew = fmaxf(mi, mx);
        float alpha = __expf(mi - mnew);
        float rs = 0.f;
#pragma unroll
        for (int r = 0; r < 16; r++) { float p = __expf(s[r] - mnew); s[r] = p; rs += p; }
        rs += __shfl_xor(rs, 32);
        li = li * alpha + rs;
        bool need = (mnew > mi);
        mi = mnew;
        // write P to LDS in B-operand row layout: key m = (r&3) + 8*(r>>2) + 4*h
#pragma unroll
        for (int pk = 0; pk < 4; pk++) {
            bf16x4 pp;
            pp[0] = (__bf16)s[pk * 4];     pp[1] = (__bf16)s[pk * 4 + 1];
            pp[2] = (__bf16)s[pk * 4 + 2]; pp[3] = (__bf16)s[pk * 4 + 3];
            *(bf16x4*)&ptile[wave][l32][pk * 8 + h * 4] = pp;
        }
        // prefetch next tile into registers (latency overlapped by PV below)
        if (it + 1 < 32) {
            const int off = (it + 1) * 32;
#pragma unroll
            for (int i = 0; i < 4; i++) {
                int c = tid + 256 * i;
                kc[i] = *(const bf16x8*)(kb + (size_t)(off + (c >> 5)) * 256 + (c & 31) * 8);
            }
#pragma unroll
            for (int j = 0; j < 4; j++)
                vc[j] = *(const bf16x8*)(vb + (size_t)tid * 4096 + off + j * 8);
        }
        if (__ballot(need)) {
#pragma unroll
            for (int ct = 0; ct < 8; ct++)
#pragma unroll
                for (int r = 0; r < 16; r++) acc[ct][r] *= alpha;
        }
        // ---- O^T += V^T . P  (P B-frags reused across 8 channel tiles) ----
        bf16x8 pf0 = *(const bf16x8*)&ptile[wave][l32][h * 8];
        bf16x8 pf1 = *(const bf16x8*)&ptile[wave][l32][16 + h * 8];
#pragma unroll
        for (int ct = 0; ct < 8; ct++) {
            bf16x8 v0 = *(const bf16x8*)&vbufs[cur][ct * 32 + l32][h * 8];
            acc[ct] = MFMA32(v0, pf0, acc[ct]);
            bf16x8 v1 = *(const bf16x8*)&vbufs[cur][ct * 32 + l32][16 + h * 8];
            acc[ct] = MFMA32(v1, pf1, acc[ct]);
        }
        // ---- stage next tile (safe: other waves read buf[cur] only) ----
        if (it + 1 < 32) {
            const int nxt = 1 - cur;
#pragma unroll
            for (int i = 0; i < 4; i++) {
                int c = tid + 256 * i;
                *(bf16x8*)&kbufs[nxt][c >> 5][(c & 31) * 8] = kc[i];
            }
#pragma unroll
            for (int j = 0; j < 4; j++)
                *(bf16x8*)&vbufs[nxt][tid][j * 8] = vc[j];
            __syncthreads();
        }
    }

    __syncthreads();   // all waves done with k/v bufs; reuse as otr
    // transpose O^T (C-layout regs) -> row-major via per-wave LDS region
#pragma unroll
    for (int ct = 0; ct < 8; ct++) {
#pragma unroll
        for (int pk = 0; pk < 4; pk++) {
            bf16x4 op;
            op[0] = (__bf16)acc[ct][pk * 4];     op[1] = (__bf16)acc[ct][pk * 4 + 1];
            op[2] = (__bf16)acc[ct][pk * 4 + 2]; op[3] = (__bf16)acc[ct][pk * 4 + 3];
            *(bf16x4*)&otr[wave][l32][ct * 32 + pk * 8 + h * 4] = op;
        }
    }
    if (lane < 32) {
        float2 v; v.x = mi; v.y = li;
        *(float2*)&ml[((size_t)ks * 16384 + rowg0 + l32) * 2] = v;
    }
    __bf16* pobase = po + ((size_t)ks * 16384 + rowg0) * 256;
    const int rr = lane >> 1, half = lane & 1;
#pragma unroll
    for (int j = 0; j < 16; j++) {
        bf16x8 val = *(const bf16x8*)&otr[wave][rr][half * 128 + j * 8];
        *(bf16x8*)(pobase + (size_t)rr * 256 + half * 128 + j * 8) = val;
    }
}

// ---------------- Merge 4 key-split partials ----------------
__global__ __launch_bounds__(256) void merge_attn(const __bf16* __restrict__ po,
                                                  const float* __restrict__ ml,
                                                  __bf16* __restrict__ ao) {
    int t = blockIdx.x * 256 + threadIdx.x;   // 0 .. 524287
    int row = t >> 5, c8 = t & 31;
    float mm[4], ll[4];
#pragma unroll
    for (int s = 0; s < 4; s++) {
        float2 v = *(const float2*)&ml[((size_t)s * 16384 + row) * 2];
        mm[s] = v.x; ll[s] = v.y;
    }
    float M = fmaxf(fmaxf(mm[0], mm[1]), fmaxf(mm[2], mm[3]));
    float den = 0.f, w[4];
#pragma unroll
    for (int s = 0; s < 4; s++) { w[s] = __expf(mm[s] - M); den += ll[s] * w[s]; }
    float accv[8];
#pragma unroll
    for (int e = 0; e < 8; e++) accv[e] = 0.f;
#pragma unroll
    for (int s = 0; s < 4; s++) {
        bf16x8 pv = *(const bf16x8*)(po + ((size_t)s * 16384 + row) * 256 + c8 * 8);
#pragma unroll
        for (int e = 0; e < 8; e++) accv[e] += w[s] * (float)pv[e];
    }
    float rinv = 1.f / den;
    bf16x8 o;
#pragma unroll
    for (int e = 0; e < 8; e++) o[e] = (__bf16)(accv[e] * rinv);
    *(bf16x8*)(ao + (size_t)row * 256 + c8 * 8) = o;
}

// ---------------- Projection GEMM + bias + residual (d_out already holds xn) ----------------
__global__ __launch_bounds__(256) void proj_gemm(const __bf16* __restrict__ ao,
                                                 const __bf16* __restrict__ wpt,
                                                 const float* __restrict__ bp,
                                                 float* __restrict__ out) {
    int wave = threadIdx.x >> 6, lane = threadIdx.x & 63;
    int quad = lane >> 4, l16 = lane & 15;
    int m0 = blockIdx.x * 64 + wave * 16;
    int n0 = blockIdx.y * 64;
    f32x4 acc[4] = {{0.f,0.f,0.f,0.f},{0.f,0.f,0.f,0.f},{0.f,0.f,0.f,0.f},{0.f,0.f,0.f,0.f}};
    const __bf16* arow = ao + (size_t)(m0 + l16) * 256 + quad * 8;
#pragma unroll
    for (int k = 0; k < 256; k += 32) {
        bf16x8 af = *(const bf16x8*)(arow + k);
#pragma unroll
        for (int ct = 0; ct < 4; ct++) {
            bf16x8 bf = *(const bf16x8*)(wpt + (size_t)(n0 + ct * 16 + l16) * 256 + k + quad * 8);
            acc[ct] = MFMA16(af, bf, acc[ct]);
        }
    }
#pragma unroll
    for (int ct = 0; ct < 4; ct++) {
        int c = n0 + ct * 16 + l16;
        float bias_v = bp[c];
#pragma unroll
        for (int r = 0; r < 4; r++) {
            int m = m0 + quad * 4 + r;
            size_t idx = (size_t)m * 256 + c;
            out[idx] = out[idx] + acc[ct][r] + bias_v;
        }
    }
}

extern "C" void kernel_launch(void* const* d_in, const int* in_sizes, int n_in,
                              void* d_out, int out_size, void* d_ws, size_t ws_size,
                              hipStream_t stream) {
    const float* x     = (const float*)d_in[0];
    const float* gamma = (const float*)d_in[1];
    const float* beta  = (const float*)d_in[2];
    const float* Wq    = (const float*)d_in[3];
    const float* bq    = (const float*)d_in[4];
    const float* Wk    = (const float*)d_in[5];
    const float* bk    = (const float*)d_in[6];
    const float* Wv    = (const float*)d_in[7];
    const float* bv    = (const float*)d_in[8];
    const float* Wp    = (const float*)d_in[9];
    const float* bp    = (const float*)d_in[10];
    float* out = (float*)d_out;

    char* ws = (char*)d_ws;
    __bf16* xn_bf   = (__bf16*)(ws);                    //  8,388,608 B
    __bf16* wt      = (__bf16*)(ws + 8388608);          //    524,288 B
    __bf16* qbuf    = (__bf16*)(ws + 8912896);          //  8,388,608 B (aliased by aobuf after flash)
    __bf16* kbuf    = (__bf16*)(ws + 17301504);         //  8,388,608 B
    __bf16* vtbuf   = (__bf16*)(ws + 25690112);         //  8,388,608 B
    __bf16* po      = (__bf16*)(ws + 34078720);         // 33,554,432 B (4 ksplit partials)
    float*  ml      = (float*)(ws + 67633152);          //    524,288 B
    float*  pstats  = (float*)(ws + 68157440);          //      4,096 B
    float*  gstats  = (float*)(ws + 68161536);          //        256 B
    __bf16* aobuf   = qbuf;                              // reuse (q dead after flash)

    gn_stats1<<<512, 256, 0, stream>>>(x, pstats);
    gn_stats2<<<1, 64, 0, stream>>>(pstats, gstats);
    gn_norm<<<4096, 256, 0, stream>>>(x, gamma, beta, gstats, out, xn_bf);
    prep_w<<<1024, 256, 0, stream>>>(Wq, Wk, Wv, Wp, wt);
    qkv_gemm<<<dim3(64, 4, 3), 256, 0, stream>>>(xn_bf, wt, bq, bk, bv, qbuf, kbuf, vtbuf);
    flash_attn<<<dim3(32, 4, 4), 256, 0, stream>>>(qbuf, kbuf, vtbuf, po, ml);
    merge_attn<<<2048, 256, 0, stream>>>(po, ml, aobuf);
    proj_gemm<<<dim3(256, 4), 256, 0, stream>>>(aobuf, wt + 3 * 65536, bp, out);
}